// Round 1
// baseline (5004.630 us; speedup 1.0000x reference)
//
#include <hip/hip_runtime.h>

#define BB 16
#define LL 512
#define DD 128

// ---------------- transpose Wq, Wk, Wout (once per call, tiny) ----------------
__global__ void transpose3_kernel(const float* __restrict__ Wq,
                                  const float* __restrict__ Wk,
                                  const float* __restrict__ Wout,
                                  float* __restrict__ WqT,
                                  float* __restrict__ WkT,
                                  float* __restrict__ WoutT) {
    const float* src; float* dst;
    if (blockIdx.x == 0)      { src = Wq;   dst = WqT;   }
    else if (blockIdx.x == 1) { src = Wk;   dst = WkT;   }
    else                      { src = Wout; dst = WoutT; }
    for (int idx = threadIdx.x; idx < DD * DD; idx += blockDim.x) {
        int r = idx >> 7, c = idx & 127;
        dst[c * DD + r] = src[idx];
    }
}

// ---------------- prologue: q/k projections, k-normalize, P0 rotation, poly ----
// one block handles 4 (b,l) rows; 128 threads, thread = output feature e.
__global__ __launch_bounds__(128) void prologue_kernel(
        const float* __restrict__ x, const float* __restrict__ WqT,
        const float* __restrict__ WkT, const float* __restrict__ P0,
        const float* __restrict__ log_gain, const float* __restrict__ coeffs,
        float* __restrict__ kphi, float* __restrict__ qphi) {
    const int row0 = blockIdx.x * 4;
    const int e = threadIdx.x;
    __shared__ float xs[4][DD];
    __shared__ float qrow[4][DD];
    __shared__ float wred[4][2];

    #pragma unroll
    for (int rr = 0; rr < 4; ++rr)
        xs[rr][e] = x[(size_t)(row0 + rr) * DD + e];
    __syncthreads();

    float aq[4] = {0,0,0,0}, ak[4] = {0,0,0,0};
    #pragma unroll 4
    for (int d = 0; d < DD; ++d) {
        float wq = WqT[d * DD + e];
        float wk = WkT[d * DD + e];
        #pragma unroll
        for (int rr = 0; rr < 4; ++rr) {
            float xv = xs[rr][d];
            aq[rr] = fmaf(xv, wq, aq[rr]);
            ak[rr] = fmaf(xv, wk, ak[rr]);
        }
    }
    const int lane = threadIdx.x & 63, wv = threadIdx.x >> 6;
    #pragma unroll
    for (int rr = 0; rr < 4; ++rr) {
        float s = ak[rr] * ak[rr];
        #pragma unroll
        for (int m = 1; m <= 32; m <<= 1) s += __shfl_xor(s, m);
        if (lane == 0) wred[rr][wv] = s;
    }
    __syncthreads();
    const float c0 = coeffs[0], c1v = coeffs[1];
    #pragma unroll
    for (int rr = 0; rr < 4; ++rr) {
        float s = wred[rr][0] + wred[rr][1];
        float kn = ak[rr] / fmaxf(sqrtf(s), 1e-12f);
        kphi[(size_t)(row0 + rr) * DD + e] = c0 * kn + c1v * kn * kn;
        qrow[rr][e] = aq[rr];
    }
    __syncthreads();
    float acc[4] = {0,0,0,0};
    #pragma unroll 4
    for (int d = 0; d < DD; ++d) {
        float pv = P0[d * DD + e];
        #pragma unroll
        for (int rr = 0; rr < 4; ++rr) acc[rr] = fmaf(qrow[rr][d], pv, acc[rr]);
    }
    const float g = expf(log_gain[e]);
    #pragma unroll
    for (int rr = 0; rr < 4; ++rr) {
        float qa = tanhf(g * acc[rr]);
        qphi[(size_t)(row0 + rr) * DD + e] = c0 * qa + c1v * qa * qa;
    }
}

// ---------------- main sequential scan: one block per batch --------------------
// 1024 threads; thread t owns row r = t>>3, cols [16*(t&7), +16) of S, S^T, A, M
// in registers. Row-matvecs reduce over 8 lanes (shfl_xor 1,2,4). Column-side
// matvecs run on the register-resident transpose ST. A = S S^T S is maintained
// by an exact rank-3 recurrence (see header comment in kernel).
__global__ __launch_bounds__(1024) void scan_kernel(
        const float* __restrict__ kphi, const float* __restrict__ qphi,
        const float* __restrict__ x, const float* __restrict__ M0,
        const float* __restrict__ S0, float* __restrict__ ys) {
    const int b   = blockIdx.x;
    const int tid = threadIdx.x;
    const int r   = tid >> 3;
    const int j   = tid & 7;
    const int cb  = j * 16;

    __shared__ __align__(16) float ks[2][DD], qs[2][DD], xrow[2][DD];
    __shared__ __align__(16) float us[DD], ps[DD], wsv[DD], hs[DD];
    __shared__ float red[DD];
    __shared__ float n2sh[2];

    float S[16], ST[16], A[16], M[16];
    const size_t mbase = (size_t)r * DD + cb;
    #pragma unroll
    for (int i = 0; i < 16; ++i) {
        S[i]  = S0[mbase + i];
        M[i]  = M0[mbase + i];
        ST[i] = S0[(size_t)(cb + i) * DD + r];
        A[i]  = 0.f;   // exact when S0 == 0 (A = S0 S0^T S0)
    }

    // ||S0||^2 (block reduction), and preload t=0 vectors
    float sp = 0.f;
    #pragma unroll
    for (int i = 0; i < 16; ++i) sp = fmaf(S[i], S[i], sp);
    sp += __shfl_xor(sp, 1); sp += __shfl_xor(sp, 2); sp += __shfl_xor(sp, 4);
    if (j == 0) red[r] = sp;

    const size_t base = (size_t)b * LL * DD;
    if (tid < 32)       ((float4*)ks[0])[tid]      = ((const float4*)(kphi + base))[tid];
    else if (tid < 64)  ((float4*)qs[0])[tid - 32] = ((const float4*)(qphi + base))[tid - 32];
    else if (tid < 96)  ((float4*)xrow[0])[tid-64] = ((const float4*)(x + base))[tid - 64];
    __syncthreads();
    if (tid < 128) {
        float s = red[tid];
        #pragma unroll
        for (int m = 1; m <= 32; m <<= 1) s += __shfl_xor(s, m);
        if ((tid & 63) == 0) n2sh[tid >> 6] = s;
    }
    __syncthreads();
    float n2 = n2sh[0] + n2sh[1];

    const float a = 0.9f, a2v = 0.81f, a3v = 0.729f;

    for (int t = 0; t < LL; ++t) {
        const int buf = t & 1, nbuf = buf ^ 1;

        // ---- phase 2: pred = M k, p = S v, cv = v.v  (old M, S) ----
        float predp = 0.f, pp = 0.f, cvp = 0.f;
        const float4* k4 = (const float4*)&ks[buf][cb];
        #pragma unroll
        for (int i4 = 0; i4 < 4; ++i4) {
            float4 v4 = k4[i4];
            float vv[4] = {v4.x, v4.y, v4.z, v4.w};
            #pragma unroll
            for (int l = 0; l < 4; ++l) {
                int i = i4 * 4 + l;
                predp = fmaf(M[i], vv[l], predp);
                pp    = fmaf(S[i], vv[l], pp);
                cvp   = fmaf(vv[l], vv[l], cvp);
            }
        }
        predp += __shfl_xor(predp,1); predp += __shfl_xor(predp,2); predp += __shfl_xor(predp,4);
        pp    += __shfl_xor(pp,1);    pp    += __shfl_xor(pp,2);    pp    += __shfl_xor(pp,4);
        cvp   += __shfl_xor(cvp,1);   cvp   += __shfl_xor(cvp,2);   cvp   += __shfl_xor(cvp,4);
        const float x_r = xrow[buf][r];
        const float u_r = predp - x_r;   // err
        const float p_r = pp;
        const float cv  = cvp;
        const float v_r = ks[buf][r];
        if (j == 0) { us[r] = u_r; ps[r] = p_r; }
        __syncthreads();

        // ---- phase 4: w = S^T u, h = S^T p, dots; then ST <- a ST + v u^T ----
        float wp = 0.f, hp = 0.f, cup = 0.f, cuu = 0.f;
        const float4* u4p = (const float4*)&us[cb];
        const float4* p4p = (const float4*)&ps[cb];
        #pragma unroll
        for (int i4 = 0; i4 < 4; ++i4) {
            float4 u4 = u4p[i4], pq = p4p[i4];
            float uu[4] = {u4.x, u4.y, u4.z, u4.w};
            float pa[4] = {pq.x, pq.y, pq.z, pq.w};
            #pragma unroll
            for (int l = 0; l < 4; ++l) {
                int i = i4 * 4 + l;
                wp  = fmaf(ST[i], uu[l], wp);
                hp  = fmaf(ST[i], pa[l], hp);
                cuu = fmaf(uu[l], uu[l], cuu);
                cup = fmaf(uu[l], pa[l], cup);
                ST[i] = fmaf(a, ST[i], v_r * uu[l]);   // uses old ST above only
            }
        }
        wp  += __shfl_xor(wp,1);  wp  += __shfl_xor(wp,2);  wp  += __shfl_xor(wp,4);
        hp  += __shfl_xor(hp,1);  hp  += __shfl_xor(hp,2);  hp  += __shfl_xor(hp,4);
        cuu += __shfl_xor(cuu,1); cuu += __shfl_xor(cuu,2); cuu += __shfl_xor(cuu,4);
        cup += __shfl_xor(cup,1); cup += __shfl_xor(cup,2); cup += __shfl_xor(cup,4);
        n2 = a2v * n2 + 2.0f * a * cup + cuu * cv;    // ||S_t||_F^2, exact recurrence
        if (j == 0) { wsv[r] = wp; hs[r] = hp; }

        // prefetch next step's k_phi / q_phi / x rows into the other buffer
        const int tn = (t + 1 < LL) ? (t + 1) : (LL - 1);
        const size_t nb = base + (size_t)tn * DD;
        if (tid >= 896 && tid < 928)
            ((float4*)ks[nbuf])[tid - 896]   = ((const float4*)(kphi + nb))[tid - 896];
        else if (tid >= 928 && tid < 960)
            ((float4*)qs[nbuf])[tid - 928]   = ((const float4*)(qphi + nb))[tid - 928];
        else if (tid >= 960 && tid < 992)
            ((float4*)xrow[nbuf])[tid - 960] = ((const float4*)(x + nb))[tid - 960];
        __syncthreads();

        // ---- phase 6: g = S w; rank-3 update of A; S, M updates; y = M q ----
        float wch[16];
        {
            const float4* w4p = (const float4*)&wsv[cb];
            #pragma unroll
            for (int i4 = 0; i4 < 4; ++i4) {
                float4 w4 = w4p[i4];
                wch[i4*4+0] = w4.x; wch[i4*4+1] = w4.y;
                wch[i4*4+2] = w4.z; wch[i4*4+3] = w4.w;
            }
        }
        float gp = 0.f;
        #pragma unroll
        for (int i = 0; i < 16; ++i) gp = fmaf(S[i], wch[i], gp);
        gp += __shfl_xor(gp,1); gp += __shfl_xor(gp,2); gp += __shfl_xor(gp,4);

        const float cu  = cuu;
        const float rho = a2v * gp + a * cu * p_r + (a * cup + cv * cu) * u_r;
        const float sig = a2v * p_r + a * cv * u_r;
        const float tau = a2v * u_r;
        const float n   = sqrtf(fmaxf(n2, 0.f)) + 1e-6f;
        const float rn  = 1.0f / n;
        const float c1  = -0.015f * rn;            // 0.99M - 0.01*(1.5 S/n - 0.5 A/n^3)
        const float c2  = 0.005f * rn * rn * rn;

        float yp = 0.f;
        const float4* kk4 = (const float4*)&ks[buf][cb];
        const float4* h4p = (const float4*)&hs[cb];
        const float4* q4p = (const float4*)&qs[buf][cb];
        #pragma unroll
        for (int i4 = 0; i4 < 4; ++i4) {
            float4 v4 = kk4[i4], h4 = h4p[i4], q4 = q4p[i4];
            float vv[4] = {v4.x, v4.y, v4.z, v4.w};
            float hh[4] = {h4.x, h4.y, h4.z, h4.w};
            float qq[4] = {q4.x, q4.y, q4.z, q4.w};
            #pragma unroll
            for (int l = 0; l < 4; ++l) {
                int i = i4 * 4 + l;
                S[i] = fmaf(a, S[i], u_r * vv[l]);
                A[i] = fmaf(a3v, A[i],
                         fmaf(rho, vv[l], fmaf(sig, wch[i], tau * hh[l])));
                M[i] = fmaf(0.99f, M[i], fmaf(c1, S[i], c2 * A[i]));
                yp   = fmaf(M[i], qq[l], yp);
            }
        }
        yp += __shfl_xor(yp,1); yp += __shfl_xor(yp,2); yp += __shfl_xor(yp,4);
        if (j == 0) ys[base + (size_t)t * DD + r] = yp;
    }
}

// ---------------- epilogue: out = ys @ Wout^T + bout ---------------------------
__global__ __launch_bounds__(128) void epilogue_kernel(
        const float* __restrict__ ys, const float* __restrict__ WoutT,
        const float* __restrict__ bout, float* __restrict__ out) {
    const int row0 = blockIdx.x * 4;
    const int e = threadIdx.x;
    __shared__ float yr[4][DD];
    #pragma unroll
    for (int rr = 0; rr < 4; ++rr)
        yr[rr][e] = ys[(size_t)(row0 + rr) * DD + e];
    __syncthreads();
    float acc[4] = {0,0,0,0};
    #pragma unroll 4
    for (int d = 0; d < DD; ++d) {
        float w = WoutT[d * DD + e];
        #pragma unroll
        for (int rr = 0; rr < 4; ++rr) acc[rr] = fmaf(yr[rr][d], w, acc[rr]);
    }
    const float bo = bout[e];
    #pragma unroll
    for (int rr = 0; rr < 4; ++rr)
        out[(size_t)(row0 + rr) * DD + e] = acc[rr] + bo;
}

extern "C" void kernel_launch(void* const* d_in, const int* in_sizes, int n_in,
                              void* d_out, int out_size, void* d_ws, size_t ws_size,
                              hipStream_t stream) {
    const float* x        = (const float*)d_in[0];
    const float* Wq       = (const float*)d_in[1];
    const float* Wk       = (const float*)d_in[2];
    const float* P0       = (const float*)d_in[3];
    const float* M0       = (const float*)d_in[4];
    const float* S0       = (const float*)d_in[5];
    const float* log_gain = (const float*)d_in[6];
    const float* coeffs   = (const float*)d_in[7];
    const float* Wout     = (const float*)d_in[8];
    const float* bout     = (const float*)d_in[9];
    float* out = (float*)d_out;

    float* ws    = (float*)d_ws;            // needs ~6.5 MB of workspace
    float* WqT   = ws;                      // 16384
    float* WkT   = ws + 16384;              // 16384
    float* WoutT = ws + 32768;              // 16384
    float* kphi  = ws + 49152;              // B*L*D = 1048576... (524288 each)
    float* qphi  = kphi + (size_t)BB * LL * DD;
    float* ysb   = qphi + (size_t)BB * LL * DD;

    hipLaunchKernelGGL(transpose3_kernel, dim3(3), dim3(256), 0, stream,
                       Wq, Wk, Wout, WqT, WkT, WoutT);
    hipLaunchKernelGGL(prologue_kernel, dim3(BB * LL / 4), dim3(128), 0, stream,
                       x, WqT, WkT, P0, log_gain, coeffs, kphi, qphi);
    hipLaunchKernelGGL(scan_kernel, dim3(BB), dim3(1024), 0, stream,
                       kphi, qphi, x, M0, S0, ysb);
    hipLaunchKernelGGL(epilogue_kernel, dim3(BB * LL / 4), dim3(128), 0, stream,
                       ysb, WoutT, bout, out);
}

// Round 2
// 4156.279 us; speedup vs baseline: 1.2041x; 1.2041x over previous
//
#include <hip/hip_runtime.h>

#define BB 16
#define LL 512
#define DD 128

// ---------------- transpose Wq, Wk, Wout (once per call, tiny) ----------------
__global__ void transpose3_kernel(const float* __restrict__ Wq,
                                  const float* __restrict__ Wk,
                                  const float* __restrict__ Wout,
                                  float* __restrict__ WqT,
                                  float* __restrict__ WkT,
                                  float* __restrict__ WoutT) {
    const float* src; float* dst;
    if (blockIdx.x == 0)      { src = Wq;   dst = WqT;   }
    else if (blockIdx.x == 1) { src = Wk;   dst = WkT;   }
    else                      { src = Wout; dst = WoutT; }
    for (int idx = threadIdx.x; idx < DD * DD; idx += blockDim.x) {
        int r = idx >> 7, c = idx & 127;
        dst[c * DD + r] = src[idx];
    }
}

// ---------------- prologue: q/k projections, k-normalize, P0 rotation, poly ----
__global__ __launch_bounds__(128) void prologue_kernel(
        const float* __restrict__ x, const float* __restrict__ WqT,
        const float* __restrict__ WkT, const float* __restrict__ P0,
        const float* __restrict__ log_gain, const float* __restrict__ coeffs,
        float* __restrict__ kphi, float* __restrict__ qphi) {
    const int row0 = blockIdx.x * 4;
    const int e = threadIdx.x;
    __shared__ float xs[4][DD];
    __shared__ float qrow[4][DD];
    __shared__ float wred[4][2];

    #pragma unroll
    for (int rr = 0; rr < 4; ++rr)
        xs[rr][e] = x[(size_t)(row0 + rr) * DD + e];
    __syncthreads();

    float aq[4] = {0,0,0,0}, ak[4] = {0,0,0,0};
    #pragma unroll 4
    for (int d = 0; d < DD; ++d) {
        float wq = WqT[d * DD + e];
        float wk = WkT[d * DD + e];
        #pragma unroll
        for (int rr = 0; rr < 4; ++rr) {
            float xv = xs[rr][d];
            aq[rr] = fmaf(xv, wq, aq[rr]);
            ak[rr] = fmaf(xv, wk, ak[rr]);
        }
    }
    const int lane = threadIdx.x & 63, wv = threadIdx.x >> 6;
    #pragma unroll
    for (int rr = 0; rr < 4; ++rr) {
        float s = ak[rr] * ak[rr];
        #pragma unroll
        for (int m = 1; m <= 32; m <<= 1) s += __shfl_xor(s, m);
        if (lane == 0) wred[rr][wv] = s;
    }
    __syncthreads();
    const float c0 = coeffs[0], c1v = coeffs[1];
    #pragma unroll
    for (int rr = 0; rr < 4; ++rr) {
        float s = wred[rr][0] + wred[rr][1];
        float kn = ak[rr] / fmaxf(sqrtf(s), 1e-12f);
        kphi[(size_t)(row0 + rr) * DD + e] = c0 * kn + c1v * kn * kn;
        qrow[rr][e] = aq[rr];
    }
    __syncthreads();
    float acc[4] = {0,0,0,0};
    #pragma unroll 4
    for (int d = 0; d < DD; ++d) {
        float pv = P0[d * DD + e];
        #pragma unroll
        for (int rr = 0; rr < 4; ++rr) acc[rr] = fmaf(qrow[rr][d], pv, acc[rr]);
    }
    const float g = expf(log_gain[e]);
    #pragma unroll
    for (int rr = 0; rr < 4; ++rr) {
        float qa = tanhf(g * acc[rr]);
        qphi[(size_t)(row0 + rr) * DD + e] = c0 * qa + c1v * qa * qa;
    }
}

// ---------------- main sequential scan: one block per batch --------------------
// 512 threads (8 waves, 2/SIMD, VGPR cap 256). Thread t: row r = t>>2, j = t&2b.
// Thread owns 32 columns of S, ST(=S^T slice), A, M in registers, in the
// PERMUTED chunk layout: float4 chunks at word offsets 4j + 16m (m=0..7), i.e.
// col(m,l) = 4j + 16m + l. Simultaneous b128 LDS reads across j hit 16 distinct
// banks once each -> conflict-free. Quad reductions (shfl_xor 1,2) = DPP.
// A = S S^T S maintained by exact rank-3 recurrence; ||S||_F^2 by scalar
// recurrence (identical math to the passing round-1 kernel).
__global__ __launch_bounds__(512, 2) void scan_kernel(
        const float* __restrict__ kphi, const float* __restrict__ qphi,
        const float* __restrict__ x, const float* __restrict__ M0,
        const float* __restrict__ S0, float* __restrict__ ys) {
    const int b   = blockIdx.x;
    const int tid = threadIdx.x;
    const int r   = tid >> 2;
    const int j   = tid & 3;

    __shared__ __align__(16) float kq[2][2 * DD];   // [buf][0..127]=k, [128..255]=q
    __shared__ __align__(16) float xrow[2][DD];
    __shared__ __align__(16) float us[DD], ps[DD], wsv[DD], hs[DD];
    __shared__ float red[DD];
    __shared__ float n2sh[2];

    float S[32], ST[32], A[32], M[32];
    {
        const float4* S04 = (const float4*)S0;
        const float4* M04 = (const float4*)M0;
        #pragma unroll
        for (int m = 0; m < 8; ++m) {
            int f4i = r * 32 + j + 4 * m;           // row r, words 4j+16m
            float4 s4 = S04[f4i], m4 = M04[f4i];
            S[4*m+0] = s4.x; S[4*m+1] = s4.y; S[4*m+2] = s4.z; S[4*m+3] = s4.w;
            M[4*m+0] = m4.x; M[4*m+1] = m4.y; M[4*m+2] = m4.z; M[4*m+3] = m4.w;
            #pragma unroll
            for (int l = 0; l < 4; ++l) {
                int col = 4 * j + 16 * m + l;
                ST[4*m+l] = S0[(size_t)col * DD + r];   // S[col][r]
            }
        }
    }
    #pragma unroll
    for (int i = 0; i < 32; ++i) A[i] = 0.f;        // exact when S0 == 0

    // ||S0||^2 block reduction + stage t=0 vectors
    float sp = 0.f;
    #pragma unroll
    for (int i = 0; i < 32; ++i) sp = fmaf(S[i], S[i], sp);
    sp += __shfl_xor(sp, 1); sp += __shfl_xor(sp, 2);
    if (j == 0) red[r] = sp;

    const size_t base = (size_t)b * LL * DD;
    if (tid < 64) {
        const float* src = (tid < 32) ? (kphi + base + 4 * tid)
                                      : (qphi + base + 4 * tid - 128);
        ((float4*)kq[0])[tid] = *(const float4*)src;
    } else if (tid < 96) {
        ((float4*)xrow[0])[tid - 64] = *(const float4*)(x + base + 4 * (tid - 64));
    }
    __syncthreads();
    if (tid < 128) {
        float s = red[tid];
        #pragma unroll
        for (int m = 1; m <= 32; m <<= 1) s += __shfl_xor(s, m);
        if ((tid & 63) == 0) n2sh[tid >> 6] = s;
    }
    __syncthreads();
    float n2 = n2sh[0] + n2sh[1];

    const float a = 0.9f, a2v = 0.81f, a3v = 0.729f;

    for (int t = 0; t < LL; ++t) {
        const int buf = t & 1, nbuf = buf ^ 1;

        // ---- phase 2: pred = M k, p = S v, cv = v.v  (old M, S) ----
        float predp = 0.f, pp = 0.f, cvp = 0.f;
        const float4* k4 = (const float4*)kq[buf];
        #pragma unroll
        for (int m = 0; m < 8; ++m) {
            float4 v4 = k4[j + 4 * m];
            float vv[4] = {v4.x, v4.y, v4.z, v4.w};
            #pragma unroll
            for (int l = 0; l < 4; ++l) {
                int i = 4 * m + l;
                predp = fmaf(M[i], vv[l], predp);
                pp    = fmaf(S[i], vv[l], pp);
                cvp   = fmaf(vv[l], vv[l], cvp);
            }
        }
        predp += __shfl_xor(predp, 1); predp += __shfl_xor(predp, 2);
        pp    += __shfl_xor(pp, 1);    pp    += __shfl_xor(pp, 2);
        cvp   += __shfl_xor(cvp, 1);   cvp   += __shfl_xor(cvp, 2);
        const float x_r = xrow[buf][r];
        const float u_r = predp - x_r;   // err
        const float p_r = pp;
        const float cv  = cvp;
        const float v_r = kq[buf][r];
        if (j == 0) { us[r] = u_r; ps[r] = p_r; }
        __syncthreads();                               // barrier 1

        // ---- staging loads for t+1 issued first (in flight across phase 4) ----
        const int tn = (t + 1 < LL) ? (t + 1) : (LL - 1);
        const size_t nb = base + (size_t)tn * DD;
        float4 pre;
        if (tid < 64) {
            const float* src = (tid < 32) ? (kphi + nb + 4 * tid)
                                          : (qphi + nb + 4 * tid - 128);
            pre = *(const float4*)src;
        } else if (tid < 96) {
            pre = *(const float4*)(x + nb + 4 * (tid - 64));
        }

        // ---- phase 4: w = S^T u, h = S^T p, dots; then ST <- a ST + u v^T ----
        float wp = 0.f, hp = 0.f, cup = 0.f, cuu = 0.f;
        const float4* u4p = (const float4*)us;
        const float4* p4p = (const float4*)ps;
        #pragma unroll
        for (int m = 0; m < 8; ++m) {
            float4 u4 = u4p[j + 4 * m], pq = p4p[j + 4 * m];
            float uu[4] = {u4.x, u4.y, u4.z, u4.w};
            float pa[4] = {pq.x, pq.y, pq.z, pq.w};
            #pragma unroll
            for (int l = 0; l < 4; ++l) {
                int i = 4 * m + l;
                wp  = fmaf(ST[i], uu[l], wp);
                hp  = fmaf(ST[i], pa[l], hp);
                cuu = fmaf(uu[l], uu[l], cuu);
                cup = fmaf(uu[l], pa[l], cup);
                ST[i] = fmaf(a, ST[i], v_r * uu[l]);   // old ST used above only
            }
        }
        wp  += __shfl_xor(wp, 1);  wp  += __shfl_xor(wp, 2);
        hp  += __shfl_xor(hp, 1);  hp  += __shfl_xor(hp, 2);
        cuu += __shfl_xor(cuu, 1); cuu += __shfl_xor(cuu, 2);
        cup += __shfl_xor(cup, 1); cup += __shfl_xor(cup, 2);
        n2 = a2v * n2 + 2.0f * a * cup + cuu * cv;     // ||S_t||_F^2 recurrence
        if (j == 0) { wsv[r] = wp; hs[r] = hp; }

        // commit staged rows to LDS (vmcnt waited here, after phase-4 compute)
        if (tid < 64)       ((float4*)kq[nbuf])[tid]        = pre;
        else if (tid < 96)  ((float4*)xrow[nbuf])[tid - 64] = pre;
        __syncthreads();                               // barrier 2

        // ---- phase 6: g = S w; rank-3 update of A; S, M updates; y = M q ----
        float wch[32];
        const float4* w4p = (const float4*)wsv;
        #pragma unroll
        for (int m = 0; m < 8; ++m) {
            float4 w4 = w4p[j + 4 * m];
            wch[4*m+0] = w4.x; wch[4*m+1] = w4.y;
            wch[4*m+2] = w4.z; wch[4*m+3] = w4.w;
        }
        float gp = 0.f;
        #pragma unroll
        for (int i = 0; i < 32; ++i) gp = fmaf(S[i], wch[i], gp);
        gp += __shfl_xor(gp, 1); gp += __shfl_xor(gp, 2);

        const float cu  = cuu;
        const float rho = a2v * gp + a * cu * p_r + (a * cup + cv * cu) * u_r;
        const float sig = a2v * p_r + a * cv * u_r;
        const float tau = a2v * u_r;
        const float n   = sqrtf(fmaxf(n2, 0.f)) + 1e-6f;
        const float rn  = 1.0f / n;
        const float c1  = -0.015f * rn;          // 0.99M - 0.01*(1.5 S/n - 0.5 A/n^3)
        const float c2  = 0.005f * rn * rn * rn;

        float yp = 0.f;
        const float4* h4p = (const float4*)hs;
        const float4* q4p = (const float4*)(kq[buf] + DD);
        #pragma unroll
        for (int m = 0; m < 8; ++m) {
            float4 v4 = k4[j + 4 * m], h4 = h4p[j + 4 * m], q4 = q4p[j + 4 * m];
            float vv[4] = {v4.x, v4.y, v4.z, v4.w};
            float hh[4] = {h4.x, h4.y, h4.z, h4.w};
            float qq[4] = {q4.x, q4.y, q4.z, q4.w};
            #pragma unroll
            for (int l = 0; l < 4; ++l) {
                int i = 4 * m + l;
                S[i] = fmaf(a, S[i], u_r * vv[l]);
                A[i] = fmaf(a3v, A[i],
                         fmaf(rho, vv[l], fmaf(sig, wch[i], tau * hh[l])));
                M[i] = fmaf(0.99f, M[i], fmaf(c1, S[i], c2 * A[i]));
                yp   = fmaf(M[i], qq[l], yp);
            }
        }
        yp += __shfl_xor(yp, 1); yp += __shfl_xor(yp, 2);
        if (j == 0) ys[base + (size_t)t * DD + r] = yp;
    }
}

// ---------------- epilogue: out = ys @ Wout^T + bout ---------------------------
__global__ __launch_bounds__(128) void epilogue_kernel(
        const float* __restrict__ ys, const float* __restrict__ WoutT,
        const float* __restrict__ bout, float* __restrict__ out) {
    const int row0 = blockIdx.x * 4;
    const int e = threadIdx.x;
    __shared__ float yr[4][DD];
    #pragma unroll
    for (int rr = 0; rr < 4; ++rr)
        yr[rr][e] = ys[(size_t)(row0 + rr) * DD + e];
    __syncthreads();
    float acc[4] = {0,0,0,0};
    #pragma unroll 4
    for (int d = 0; d < DD; ++d) {
        float w = WoutT[d * DD + e];
        #pragma unroll
        for (int rr = 0; rr < 4; ++rr) acc[rr] = fmaf(yr[rr][d], w, acc[rr]);
    }
    const float bo = bout[e];
    #pragma unroll
    for (int rr = 0; rr < 4; ++rr)
        out[(size_t)(row0 + rr) * DD + e] = acc[rr] + bo;
}

extern "C" void kernel_launch(void* const* d_in, const int* in_sizes, int n_in,
                              void* d_out, int out_size, void* d_ws, size_t ws_size,
                              hipStream_t stream) {
    const float* x        = (const float*)d_in[0];
    const float* Wq       = (const float*)d_in[1];
    const float* Wk       = (const float*)d_in[2];
    const float* P0       = (const float*)d_in[3];
    const float* M0       = (const float*)d_in[4];
    const float* S0       = (const float*)d_in[5];
    const float* log_gain = (const float*)d_in[6];
    const float* coeffs   = (const float*)d_in[7];
    const float* Wout     = (const float*)d_in[8];
    const float* bout     = (const float*)d_in[9];
    float* out = (float*)d_out;

    float* ws    = (float*)d_ws;
    float* WqT   = ws;                      // 16384
    float* WkT   = ws + 16384;              // 16384
    float* WoutT = ws + 32768;              // 16384
    float* kphi  = ws + 49152;              // B*L*D each below
    float* qphi  = kphi + (size_t)BB * LL * DD;
    float* ysb   = qphi + (size_t)BB * LL * DD;

    hipLaunchKernelGGL(transpose3_kernel, dim3(3), dim3(256), 0, stream,
                       Wq, Wk, Wout, WqT, WkT, WoutT);
    hipLaunchKernelGGL(prologue_kernel, dim3(BB * LL / 4), dim3(128), 0, stream,
                       x, WqT, WkT, P0, log_gain, coeffs, kphi, qphi);
    hipLaunchKernelGGL(scan_kernel, dim3(BB), dim3(512), 0, stream,
                       kphi, qphi, x, M0, S0, ysb);
    hipLaunchKernelGGL(epilogue_kernel, dim3(BB * LL / 4), dim3(128), 0, stream,
                       ysb, WoutT, bout, out);
}

// Round 3
// 3172.411 us; speedup vs baseline: 1.5775x; 1.3101x over previous
//
#include <hip/hip_runtime.h>

#define BB 16
#define LL 512
#define DD 128

// padded word index for exchanged vectors: +4 words per 16-word chunk ->
// the 8 j-lanes' float4 reads cover all 8 bank-groups (conflict-free)
#define PADW(c) ((c) + (((c) >> 4) << 2))

// 8-lane all-reduce sum (lanes within a DPP half-row), pure VALU:
// quad xor1, quad xor2, then half-row mirror pairs the two quads.
__device__ __forceinline__ float red8(float v) {
    v += __int_as_float(__builtin_amdgcn_update_dpp(
            0, __float_as_int(v), 0xB1, 0xF, 0xF, true));
    v += __int_as_float(__builtin_amdgcn_update_dpp(
            0, __float_as_int(v), 0x4E, 0xF, 0xF, true));
    v += __int_as_float(__builtin_amdgcn_update_dpp(
            0, __float_as_int(v), 0x141, 0xF, 0xF, true));
    return v;
}

// ---------------- transpose Wq, Wk, Wout (once per call, tiny) ----------------
__global__ void transpose3_kernel(const float* __restrict__ Wq,
                                  const float* __restrict__ Wk,
                                  const float* __restrict__ Wout,
                                  float* __restrict__ WqT,
                                  float* __restrict__ WkT,
                                  float* __restrict__ WoutT) {
    const float* src; float* dst;
    if (blockIdx.x == 0)      { src = Wq;   dst = WqT;   }
    else if (blockIdx.x == 1) { src = Wk;   dst = WkT;   }
    else                      { src = Wout; dst = WoutT; }
    for (int idx = threadIdx.x; idx < DD * DD; idx += blockDim.x) {
        int r = idx >> 7, c = idx & 127;
        dst[c * DD + r] = src[idx];
    }
}

// ---------------- prologue: q/k projections, k-normalize, P0 rotation, poly ----
__global__ __launch_bounds__(128) void prologue_kernel(
        const float* __restrict__ x, const float* __restrict__ WqT,
        const float* __restrict__ WkT, const float* __restrict__ P0,
        const float* __restrict__ log_gain, const float* __restrict__ coeffs,
        float* __restrict__ kphi, float* __restrict__ qphi) {
    const int row0 = blockIdx.x * 4;
    const int e = threadIdx.x;
    __shared__ float xs[4][DD];
    __shared__ float qrow[4][DD];
    __shared__ float wred[4][2];

    #pragma unroll
    for (int rr = 0; rr < 4; ++rr)
        xs[rr][e] = x[(size_t)(row0 + rr) * DD + e];
    __syncthreads();

    float aq[4] = {0,0,0,0}, ak[4] = {0,0,0,0};
    #pragma unroll 4
    for (int d = 0; d < DD; ++d) {
        float wq = WqT[d * DD + e];
        float wk = WkT[d * DD + e];
        #pragma unroll
        for (int rr = 0; rr < 4; ++rr) {
            float xv = xs[rr][d];
            aq[rr] = fmaf(xv, wq, aq[rr]);
            ak[rr] = fmaf(xv, wk, ak[rr]);
        }
    }
    const int lane = threadIdx.x & 63, wv = threadIdx.x >> 6;
    #pragma unroll
    for (int rr = 0; rr < 4; ++rr) {
        float s = ak[rr] * ak[rr];
        #pragma unroll
        for (int m = 1; m <= 32; m <<= 1) s += __shfl_xor(s, m);
        if (lane == 0) wred[rr][wv] = s;
    }
    __syncthreads();
    const float c0 = coeffs[0], c1v = coeffs[1];
    #pragma unroll
    for (int rr = 0; rr < 4; ++rr) {
        float s = wred[rr][0] + wred[rr][1];
        float kn = ak[rr] / fmaxf(sqrtf(s), 1e-12f);
        kphi[(size_t)(row0 + rr) * DD + e] = c0 * kn + c1v * kn * kn;
        qrow[rr][e] = aq[rr];
    }
    __syncthreads();
    float acc[4] = {0,0,0,0};
    #pragma unroll 4
    for (int d = 0; d < DD; ++d) {
        float pv = P0[d * DD + e];
        #pragma unroll
        for (int rr = 0; rr < 4; ++rr) acc[rr] = fmaf(qrow[rr][d], pv, acc[rr]);
    }
    const float g = expf(log_gain[e]);
    #pragma unroll
    for (int rr = 0; rr < 4; ++rr) {
        float qa = tanhf(g * acc[rr]);
        qphi[(size_t)(row0 + rr) * DD + e] = c0 * qa + c1v * qa * qa;
    }
}

// ---------------- main sequential scan: one block per batch --------------------
// 512 threads. Thread (g = tid>>3, j = tid&7): rows {2g,2g+1} x cols [16j,16j+16)
// of S, A, M; plus the transpose tile ST[c'][rho] for c' in {2g,2g+1},
// rho in [16j,16j+16). All matvec reductions are 8-lane DPP butterflies (VALU
// only, no ds_bpermute). Exchanged vectors live in bank-padded LDS (PADW).
// A = S S^T S via exact rank-3 recurrence; ||S||_F^2 via scalar recurrence.
__global__ __launch_bounds__(512, 2) void scan_kernel(
        const float* __restrict__ kphi, const float* __restrict__ qphi,
        const float* __restrict__ x, const float* __restrict__ M0,
        const float* __restrict__ S0, float* __restrict__ ys) {
    const int b   = blockIdx.x;
    const int tid = threadIdx.x;
    const int j   = tid & 7;
    const int g   = tid >> 3;
    const int r0  = 2 * g;

    __shared__ __align__(16) float kq[2][320];   // k at PADW(c), q at 160+PADW(c)
    __shared__ __align__(16) float xr[2][160];
    __shared__ __align__(16) float us[160], ps[160], wsv[160], hs[160];
    __shared__ float red[64];
    __shared__ float n2sh;

    float S[32], ST[32], A[32], M[32];
    {
        const float4* S04 = (const float4*)S0;
        const float4* M04 = (const float4*)M0;
        #pragma unroll
        for (int rl = 0; rl < 2; ++rl)
            #pragma unroll
            for (int m = 0; m < 4; ++m) {
                int f4 = (r0 + rl) * 32 + 4 * j + m;
                float4 s4 = S04[f4], m4 = M04[f4];
                int i = rl * 16 + 4 * m;
                S[i+0] = s4.x; S[i+1] = s4.y; S[i+2] = s4.z; S[i+3] = s4.w;
                M[i+0] = m4.x; M[i+1] = m4.y; M[i+2] = m4.z; M[i+3] = m4.w;
            }
        #pragma unroll
        for (int rl = 0; rl < 2; ++rl)
            #pragma unroll
            for (int cl = 0; cl < 16; ++cl)
                ST[rl*16+cl] = S0[(size_t)(16*j + cl) * DD + r0 + rl];
        #pragma unroll
        for (int i = 0; i < 32; ++i) A[i] = 0.f;   // exact when S0 == 0
    }

    // ||S0||^2 block reduction + stage t=0 vectors
    float sp = 0.f;
    #pragma unroll
    for (int i = 0; i < 32; ++i) sp = fmaf(S[i], S[i], sp);
    sp = red8(sp);
    if (j == 0) red[g] = sp;

    const size_t base = (size_t)b * LL * DD;
    if (tid < 32) {
        ((float4*)kq[0])[tid + (tid >> 2)] = *(const float4*)(kphi + base + 4 * tid);
    } else if (tid < 64) {
        int c4 = tid - 32;
        ((float4*)kq[0])[40 + c4 + (c4 >> 2)] = *(const float4*)(qphi + base + 4 * c4);
    } else if (tid < 96) {
        int c4 = tid - 64;
        ((float4*)xr[0])[c4 + (c4 >> 2)] = *(const float4*)(x + base + 4 * c4);
    }
    __syncthreads();
    if (tid < 64) {
        float s = red[tid];
        #pragma unroll
        for (int m = 1; m <= 32; m <<= 1) s += __shfl_xor(s, m);
        if (tid == 0) n2sh = s;
    }
    __syncthreads();
    float n2 = n2sh;

    const float a = 0.9f, a2v = 0.81f, a3v = 0.729f;

    for (int t = 0; t < LL; ++t) {
        const int buf = t & 1, nbuf = buf ^ 1;
        const float* kqb = kq[buf];

        // ---- phase 2 (row side): pred = M k, p = S v, cv = v.v ----
        float kk[16];
        {
            const float4* k4 = (const float4*)kqb;
            #pragma unroll
            for (int m = 0; m < 4; ++m) {
                float4 v4 = k4[5 * j + m];
                kk[4*m+0] = v4.x; kk[4*m+1] = v4.y;
                kk[4*m+2] = v4.z; kk[4*m+3] = v4.w;
            }
        }
        float pr0 = 0.f, pr1 = 0.f, pp0 = 0.f, pp1 = 0.f, cvp = 0.f;
        #pragma unroll
        for (int cl = 0; cl < 16; ++cl) {
            float kv = kk[cl];
            pr0 = fmaf(M[cl],      kv, pr0);
            pr1 = fmaf(M[16 + cl], kv, pr1);
            pp0 = fmaf(S[cl],      kv, pp0);
            pp1 = fmaf(S[16 + cl], kv, pp1);
            cvp = fmaf(kv, kv, cvp);
        }
        pr0 = red8(pr0); pr1 = red8(pr1);
        pp0 = red8(pp0); pp1 = red8(pp1);
        const float cv = red8(cvp);
        const float2 xv = *(const float2*)&xr[buf][PADW(r0)];
        const float u0 = pr0 - xv.x, u1 = pr1 - xv.y;
        const float p0 = pp0, p1 = pp1;
        if (j == 0) {
            *(float2*)&us[PADW(r0)] = make_float2(u0, u1);
            *(float2*)&ps[PADW(r0)] = make_float2(p0, p1);
        }
        __syncthreads();                               // barrier 1

        // staging loads for t+1 (in flight across phase 4)
        const int tn = (t + 1 < LL) ? (t + 1) : (LL - 1);
        const size_t nb = base + (size_t)tn * DD;
        float4 pre;
        if (tid < 32)       pre = *(const float4*)(kphi + nb + 4 * tid);
        else if (tid < 64)  pre = *(const float4*)(qphi + nb + 4 * (tid - 32));
        else if (tid < 96)  pre = *(const float4*)(x + nb + 4 * (tid - 64));

        // ---- phase 4 (col side): w = S^T u, h = S^T p, dots; ST update ----
        float uu[16], pa[16];
        {
            const float4* u4 = (const float4*)us;
            const float4* p4 = (const float4*)ps;
            #pragma unroll
            for (int m = 0; m < 4; ++m) {
                float4 a4 = u4[5 * j + m], b4 = p4[5 * j + m];
                uu[4*m+0] = a4.x; uu[4*m+1] = a4.y;
                uu[4*m+2] = a4.z; uu[4*m+3] = a4.w;
                pa[4*m+0] = b4.x; pa[4*m+1] = b4.y;
                pa[4*m+2] = b4.z; pa[4*m+3] = b4.w;
            }
        }
        const float2 vc = *(const float2*)&kqb[PADW(r0)];
        float w0 = 0.f, w1 = 0.f, h0 = 0.f, h1 = 0.f, cuup = 0.f, cupp = 0.f;
        #pragma unroll
        for (int cl = 0; cl < 16; ++cl) {
            float uv = uu[cl], pv = pa[cl];
            float st0 = ST[cl], st1 = ST[16 + cl];
            w0 = fmaf(st0, uv, w0);  w1 = fmaf(st1, uv, w1);
            h0 = fmaf(st0, pv, h0);  h1 = fmaf(st1, pv, h1);
            cuup = fmaf(uv, uv, cuup);
            cupp = fmaf(uv, pv, cupp);
            ST[cl]      = fmaf(a, st0, vc.x * uv);     // old st used above only
            ST[16 + cl] = fmaf(a, st1, vc.y * uv);
        }
        w0 = red8(w0); w1 = red8(w1); h0 = red8(h0); h1 = red8(h1);
        const float cu  = red8(cuup);
        const float cup = red8(cupp);
        n2 = a2v * n2 + 2.0f * a * cup + cu * cv;      // ||S_t||_F^2 recurrence
        if (j == 0) {
            *(float2*)&wsv[PADW(r0)] = make_float2(w0, w1);
            *(float2*)&hs[PADW(r0)]  = make_float2(h0, h1);
        }
        // commit staged rows
        if (tid < 32) {
            ((float4*)kq[nbuf])[tid + (tid >> 2)] = pre;
        } else if (tid < 64) {
            int c4 = tid - 32;
            ((float4*)kq[nbuf])[40 + c4 + (c4 >> 2)] = pre;
        } else if (tid < 96) {
            int c4 = tid - 64;
            ((float4*)xr[nbuf])[c4 + (c4 >> 2)] = pre;
        }
        __syncthreads();                               // barrier 2

        // ---- phase 6 (row side): g = S w; rank-3 A; S, M updates; y = M q ----
        float ww[16], hh[16], qq[16];
        {
            const float4* w4 = (const float4*)wsv;
            const float4* h4 = (const float4*)hs;
            const float4* q4 = (const float4*)(kqb + 160);
            #pragma unroll
            for (int m = 0; m < 4; ++m) {
                float4 a4 = w4[5 * j + m], b4 = h4[5 * j + m], c4v = q4[5 * j + m];
                ww[4*m+0] = a4.x;  ww[4*m+1] = a4.y;
                ww[4*m+2] = a4.z;  ww[4*m+3] = a4.w;
                hh[4*m+0] = b4.x;  hh[4*m+1] = b4.y;
                hh[4*m+2] = b4.z;  hh[4*m+3] = b4.w;
                qq[4*m+0] = c4v.x; qq[4*m+1] = c4v.y;
                qq[4*m+2] = c4v.z; qq[4*m+3] = c4v.w;
            }
        }
        float g0 = 0.f, g1 = 0.f;
        #pragma unroll
        for (int cl = 0; cl < 16; ++cl) {
            g0 = fmaf(S[cl],      ww[cl], g0);
            g1 = fmaf(S[16 + cl], ww[cl], g1);
        }
        g0 = red8(g0); g1 = red8(g1);

        const float rho0 = a2v * g0 + a * cu * p0 + (a * cup + cv * cu) * u0;
        const float rho1 = a2v * g1 + a * cu * p1 + (a * cup + cv * cu) * u1;
        const float sg0  = a2v * p0 + a * cv * u0;
        const float sg1  = a2v * p1 + a * cv * u1;
        const float ta0  = a2v * u0, ta1 = a2v * u1;
        const float nrm  = sqrtf(fmaxf(n2, 0.f)) + 1e-6f;
        const float rn   = 1.0f / nrm;
        const float c1   = -0.015f * rn;        // 0.99M - 0.01*(1.5 S/n - 0.5 A/n^3)
        const float c2   = 0.005f * rn * rn * rn;

        float y0 = 0.f, y1 = 0.f;
        #pragma unroll
        for (int cl = 0; cl < 16; ++cl) {
            float kv = kk[cl], wv = ww[cl], hv = hh[cl], qv = qq[cl];
            S[cl]      = fmaf(a, S[cl],      u0 * kv);
            S[16 + cl] = fmaf(a, S[16 + cl], u1 * kv);
            A[cl]      = fmaf(a3v, A[cl],
                              fmaf(rho0, kv, fmaf(sg0, wv, ta0 * hv)));
            A[16 + cl] = fmaf(a3v, A[16 + cl],
                              fmaf(rho1, kv, fmaf(sg1, wv, ta1 * hv)));
            M[cl]      = fmaf(0.99f, M[cl],      fmaf(c1, S[cl],      c2 * A[cl]));
            M[16 + cl] = fmaf(0.99f, M[16 + cl], fmaf(c1, S[16 + cl], c2 * A[16 + cl]));
            y0 = fmaf(M[cl],      qv, y0);
            y1 = fmaf(M[16 + cl], qv, y1);
        }
        y0 = red8(y0); y1 = red8(y1);
        if (j == 0)
            *(float2*)(ys + base + (size_t)t * DD + r0) = make_float2(y0, y1);
    }
}

// ---------------- epilogue: out = ys @ Wout^T + bout ---------------------------
__global__ __launch_bounds__(128) void epilogue_kernel(
        const float* __restrict__ ys, const float* __restrict__ WoutT,
        const float* __restrict__ bout, float* __restrict__ out) {
    const int row0 = blockIdx.x * 4;
    const int e = threadIdx.x;
    __shared__ float yr[4][DD];
    #pragma unroll
    for (int rr = 0; rr < 4; ++rr)
        yr[rr][e] = ys[(size_t)(row0 + rr) * DD + e];
    __syncthreads();
    float acc[4] = {0,0,0,0};
    #pragma unroll 4
    for (int d = 0; d < DD; ++d) {
        float w = WoutT[d * DD + e];
        #pragma unroll
        for (int rr = 0; rr < 4; ++rr) acc[rr] = fmaf(yr[rr][d], w, acc[rr]);
    }
    const float bo = bout[e];
    #pragma unroll
    for (int rr = 0; rr < 4; ++rr)
        out[(size_t)(row0 + rr) * DD + e] = acc[rr] + bo;
}

extern "C" void kernel_launch(void* const* d_in, const int* in_sizes, int n_in,
                              void* d_out, int out_size, void* d_ws, size_t ws_size,
                              hipStream_t stream) {
    const float* x        = (const float*)d_in[0];
    const float* Wq       = (const float*)d_in[1];
    const float* Wk       = (const float*)d_in[2];
    const float* P0       = (const float*)d_in[3];
    const float* M0       = (const float*)d_in[4];
    const float* S0       = (const float*)d_in[5];
    const float* log_gain = (const float*)d_in[6];
    const float* coeffs   = (const float*)d_in[7];
    const float* Wout     = (const float*)d_in[8];
    const float* bout     = (const float*)d_in[9];
    float* out = (float*)d_out;

    float* ws    = (float*)d_ws;
    float* WqT   = ws;                      // 16384
    float* WkT   = ws + 16384;              // 16384
    float* WoutT = ws + 32768;              // 16384
    float* kphi  = ws + 49152;              // B*L*D each below
    float* qphi  = kphi + (size_t)BB * LL * DD;
    float* ysb   = qphi + (size_t)BB * LL * DD;

    hipLaunchKernelGGL(transpose3_kernel, dim3(3), dim3(256), 0, stream,
                       Wq, Wk, Wout, WqT, WkT, WoutT);
    hipLaunchKernelGGL(prologue_kernel, dim3(BB * LL / 4), dim3(128), 0, stream,
                       x, WqT, WkT, P0, log_gain, coeffs, kphi, qphi);
    hipLaunchKernelGGL(scan_kernel, dim3(BB), dim3(512), 0, stream,
                       kphi, qphi, x, M0, S0, ysb);
    hipLaunchKernelGGL(epilogue_kernel, dim3(BB * LL / 4), dim3(128), 0, stream,
                       ysb, WoutT, bout, out);
}